// Round 8
// baseline (1579.917 us; speedup 1.0000x reference)
//
#include <hip/hip_runtime.h>
#include <hip/hip_bf16.h>

typedef __attribute__((ext_vector_type(8))) short bfrag;
typedef __attribute__((ext_vector_type(4))) float f32x4;

// fast shifted softplus: __logf/__expf intrinsics (rel err ~2^-21, threshold 2.3e-2)
__device__ __forceinline__ float ssp_f(float x) {
    return fmaxf(x, 0.f) + __logf(1.f + __expf(-fabsf(x))) - 0.6931471805599453f;
}

__device__ __forceinline__ unsigned short f2b(float x) {
    __hip_bfloat16 h = __float2bfloat16(x);
    return *(unsigned short*)&h;
}

__device__ __forceinline__ unsigned int pk2(float a, float b) {
    __hip_bfloat162 h2 = __float22bfloat162_rn(make_float2(a, b));
    return *(unsigned int*)&h2;
}

// ---------------- float dtype sniffer ----------------------------------------
__global__ void sniff_kernel(const unsigned int* __restrict__ raw, int* __restrict__ flag)
{
    __shared__ int cnt[256];
    const int t = threadIdx.x;
    unsigned int w = raw[t];
    unsigned int e = (w >> 7) & 0xFFu;
    cnt[t] = (e >= 100u && e <= 135u) ? 1 : 0;
    __syncthreads();
    for (int s = 128; s > 0; s >>= 1) {
        if (t < s) cnt[t] += cnt[t + s];
        __syncthreads();
    }
    if (t == 0) *flag = (cnt[0] >= 160) ? 1 : 0;   // 1 = floats are bf16
}

// ---------------- int width sniffer -------------------------------------------
__global__ void sniff_int_kernel(const unsigned int* __restrict__ z, int* __restrict__ iflag)
{
    __shared__ int cnt[128];
    const int t = threadIdx.x;
    cnt[t] = (z[2 * t + 1] == 0u) ? 1 : 0;
    __syncthreads();
    for (int s = 64; s > 0; s >>= 1) {
        if (t < s) cnt[t] += cnt[t + s];
        __syncthreads();
    }
    if (t == 0) *iflag = (cnt[0] >= 126) ? 1 : 0;  // 1 = ints are int64
}

// ---------------- fused convert of all 16 float tensors -----------------------
struct Cvt16 {
    const void* src[16];
    long off[17];
};

__global__ __launch_bounds__(256) void convert_fused_kernel(
    Cvt16 args, float* __restrict__ F, long total, const int* __restrict__ flag)
{
    long i = (long)blockIdx.x * 256 + threadIdx.x;
    if (i >= total) return;
    int lo = 0, hi = 16;
    while (hi - lo > 1) {
        int mid = (lo + hi) >> 1;
        if (i >= args.off[mid]) lo = mid; else hi = mid;
    }
    long loc = i - args.off[lo];
    if (*flag) F[i] = __bfloat162float(((const __hip_bfloat16*)args.src[lo])[loc]);
    else       F[i] = ((const float*)args.src[lo])[loc];
}

__global__ __launch_bounds__(256) void convert_int_kernel(
    const void* __restrict__ src, int* __restrict__ dst, int n,
    const int* __restrict__ iflag)
{
    int i = blockIdx.x * 256 + threadIdx.x;
    if (i >= n) return;
    if (*iflag) dst[i] = (int)(((const long long*)src)[i]);
    else        dst[i] = ((const int*)src)[i];
}

// ---------------- node embedding gather (fallback path) ------------------------
__global__ __launch_bounds__(256) void embed_kernel(
    const int* __restrict__ z, const float* __restrict__ embf,
    float* __restrict__ h, int NH)
{
    int idx = blockIdx.x * 256 + threadIdx.x;
    if (idx >= NH) return;
    h[idx] = embf[z[idx >> 7] * 128 + (idx & 127)];
}

// ---------------- CSR build ----------------------------------------------------
__global__ __launch_bounds__(256) void zero_int_kernel(int* p, int n)
{
    int i = blockIdx.x * 256 + threadIdx.x;
    if (i < n) p[i] = 0;
}

__global__ __launch_bounds__(256) void hist_kernel(const int* __restrict__ col,
                                                   int* __restrict__ count, int E)
{
    int e = blockIdx.x * 256 + threadIdx.x;
    if (e < E) atomicAdd(&count[col[e]], 1);
}

__global__ __launch_bounds__(256) void scan_kernel(const int* __restrict__ count,
                                                   int* __restrict__ rowptr,
                                                   int* __restrict__ next, int N)
{
    __shared__ int part[256];
    const int t = threadIdx.x;
    const int chunk = (N + 255) / 256;
    const int lo = t * chunk, hi = min(lo + chunk, N);
    int s = 0;
    for (int i = lo; i < hi; ++i) s += count[i];
    part[t] = s;
    __syncthreads();
    if (t == 0) {
        int run = 0;
        for (int i = 0; i < 256; ++i) { int v = part[i]; part[i] = run; run += v; }
        rowptr[N] = run;
    }
    __syncthreads();
    int run = part[t];
    for (int i = lo; i < hi; ++i) {
        rowptr[i] = run; next[i] = run;
        run += count[i];
    }
}

// fused slot+perm+prep: scatter edge data directly into col-sorted order
__global__ __launch_bounds__(256) void prep_scatter_kernel(
    const float* __restrict__ posf, const int* __restrict__ row,
    const int* __restrict__ col, const float* __restrict__ eattrf,
    int* __restrict__ next,
    int* __restrict__ rowS, int* __restrict__ colS,
    float* __restrict__ CS, float* __restrict__ ewS,
    unsigned short* __restrict__ eaS, int E, int NB)
{
    int e = blockIdx.x * 256 + threadIdx.x;
    if (e >= E) return;
    const int r = row[e], c = col[e];
    const int p = atomicAdd(&next[c], 1);
    float dx = posf[r*3+0] - posf[c*3+0];
    float dy = posf[r*3+1] - posf[c*3+1];
    float dz = posf[r*3+2] - posf[c*3+2];
    float ew = sqrtf(dx*dx + dy*dy + dz*dz);
    rowS[p] = r; colS[p] = c; ewS[p] = ew;
    CS[p] = 0.5f * (cosf(ew * 0.3141592653589793f) + 1.0f);
    unsigned short* o = eaS + (long)p * 4;
    for (int q = 0; q < 4; ++q)
        o[q] = (q < NB) ? f2b(eattrf[(long)e * NB + q]) : (unsigned short)0;
}

// ---------------- fused weight transpose (fast path): all tensors in one ------
// layout: [0,A): w1t (L x 128 x 64)  [A,A+B): w2t (L x 128 x 128)
//         [A+B,A+B+C): nwt (3L x 128 x 128)   [A+B+C, +8192): o1t (64 x 128)
__global__ __launch_bounds__(256) void wtrans_all_kernel(
    const float* __restrict__ w1, const float* __restrict__ w2,
    const float* __restrict__ cf1, const float* __restrict__ cf2,
    const float* __restrict__ lin, const float* __restrict__ o1,
    unsigned short* __restrict__ w1t, unsigned short* __restrict__ w2t,
    unsigned short* __restrict__ nwt, unsigned short* __restrict__ o1t,
    int L, int F50, int total)
{
    int idx = blockIdx.x * 256 + threadIdx.x;
    if (idx >= total) return;
    const int A  = L * 8192;
    const int Bq = L * 16384;
    const int Cq = 3 * L * 16384;
    if (idx < A) {
        const int l = idx >> 13, local = idx & 8191;
        const int n = local >> 6, k = local & 63;
        w1t[idx] = (k < F50) ? f2b(w1[(long)l * F50 * 128 + k * 128 + n]) : (unsigned short)0;
    } else if (idx < A + Bq) {
        const int j = idx - A;
        const int l = j >> 14, local = j & 16383;
        const int n = local >> 7, k = local & 127;
        w2t[j] = f2b(w2[(long)l * 16384 + k * 128 + n]);
    } else if (idx < A + Bq + Cq) {
        const int j = idx - A - Bq;
        const int m = j >> 14;
        const int fam = m % 3, l = m / 3;
        const int local = j & 16383;
        const int n = local >> 7, k = local & 127;
        const float* src = (fam == 0 ? cf1 : fam == 1 ? cf2 : lin) + (long)l * 16384;
        nwt[j] = f2b(src[k * 128 + n]);
    } else {
        const int j = idx - A - Bq - Cq;
        const int n = j >> 7, k = j & 127;
        o1t[j] = f2b(o1[k * 64 + n]);
    }
}

// ---------------- fp32 node GEMM (fallback path only) -------------------------
template<int MODE>
__global__ __launch_bounds__(256) void node_gemm_tiled(
    const float* __restrict__ in, const float* __restrict__ W,
    const float* __restrict__ bias, float* __restrict__ out, int N)
{
    __shared__ float in_s[32][128];
    const int t = threadIdx.x;
    const long n0 = (long)blockIdx.x * 32;
    for (int i = t; i < 32 * 128; i += 256) {
        long n = n0 + (i >> 7);
        in_s[i >> 7][i & 127] = (n < N) ? in[n * 128 + (i & 127)] : 0.f;
    }
    __syncthreads();
    const int j = t & 31, sub = t >> 5;
    const int c4 = j * 4, rb = sub * 4;
    float acc[4][4];
    float4 bv = make_float4(0.f, 0.f, 0.f, 0.f);
    if (MODE != 0) bv = *(const float4*)(bias + c4);
    #pragma unroll
    for (int i = 0; i < 4; ++i) { acc[i][0]=bv.x; acc[i][1]=bv.y; acc[i][2]=bv.z; acc[i][3]=bv.w; }
    #pragma unroll 4
    for (int k = 0; k < 128; ++k) {
        const float4 wv = *(const float4*)(W + k * 128 + c4);
        #pragma unroll
        for (int i = 0; i < 4; ++i) {
            const float a = in_s[rb + i][k];
            acc[i][0] += a * wv.x; acc[i][1] += a * wv.y;
            acc[i][2] += a * wv.z; acc[i][3] += a * wv.w;
        }
    }
    #pragma unroll
    for (int i = 0; i < 4; ++i) {
        long n = n0 + rb + i;
        if (n >= N) continue;
        float4 o;
        if (MODE == 1) {
            o.x = ssp_f(acc[i][0]); o.y = ssp_f(acc[i][1]);
            o.z = ssp_f(acc[i][2]); o.w = ssp_f(acc[i][3]);
        } else {
            o.x = acc[i][0]; o.y = acc[i][1]; o.z = acc[i][2]; o.w = acc[i][3];
        }
        if (MODE == 2) {
            float4 p = *(const float4*)(out + n * 128 + c4);
            o.x += p.x; o.y += p.y; o.z += p.z; o.w += p.w;
        }
        *(float4*)(out + n * 128 + c4) = o;
    }
}

// ------- MFMA node GEMM, 16-row tile: xh = emb[z] @ cf1, writes h, zeroes agg --
__global__ __launch_bounds__(256) void node_gemm1_embed_mfma(
    const int* __restrict__ zi, const float* __restrict__ embf,
    const unsigned short* __restrict__ wt,
    float* __restrict__ h, float* __restrict__ out, float* __restrict__ aggz, int N)
{
    __shared__ __align__(16) short a_b[16][136];
    const int t = threadIdx.x;
    const long r0 = (long)blockIdx.x * 16;
    const float4 z4 = make_float4(0.f, 0.f, 0.f, 0.f);
    #pragma unroll
    for (int j = 0; j < 2; ++j) {
        const int fi = t + j * 256;          // float4 index 0..511
        const int r = fi >> 5, c4 = (fi & 31) << 2;
        const long n = r0 + r;
        float4 v = z4;
        if (n < N) {
            v = *(const float4*)(embf + (long)zi[n] * 128 + c4);
            *(float4*)(h + n * 128 + c4) = v;       // materialize h = emb[z]
            *(float4*)(aggz + n * 128 + c4) = z4;   // zero agg slice
        }
        *(uint2*)&a_b[r][c4] = make_uint2(pk2(v.x, v.y), pk2(v.z, v.w));
    }
    __syncthreads();
    const int lane = t & 63, w = t >> 6;
    const int colL = lane & 15, quad = lane >> 4;
    const int nh = w * 32;
    f32x4 acc[2];
    #pragma unroll
    for (int tt = 0; tt < 2; ++tt) acc[tt] = (f32x4){0.f, 0.f, 0.f, 0.f};
    #pragma unroll
    for (int ks = 0; ks < 4; ++ks) {
        const bfrag a = *(const bfrag*)&a_b[colL][ks * 32 + quad * 8];
        #pragma unroll
        for (int tt = 0; tt < 2; ++tt) {
            const bfrag wf = *(const bfrag*)&wt[(long)(nh + tt * 16 + colL) * 128 + ks * 32 + quad * 8];
            acc[tt] = __builtin_amdgcn_mfma_f32_16x16x32_bf16(wf, a, acc[tt], 0, 0, 0);
        }
    }
    const long node = r0 + colL;
    if (node < N) {
        float* orow = out + node * 128;
        #pragma unroll
        for (int tt = 0; tt < 2; ++tt) {
            const int c0 = nh + tt * 16 + quad * 4;
            *(float4*)(orow + c0) = make_float4(acc[tt][0], acc[tt][1], acc[tt][2], acc[tt][3]);
        }
    }
}

// ------- MFMA fused node block, 16-row tile ------------------------------------
// h += lin(ssp(agg @ cf2 + b2)) + blin; CHAIN=1 additionally computes next
// layer's xh = h_new @ cf1_next and zeroes the agg slice.
template<int CHAIN>
__global__ __launch_bounds__(256) void node_gemm23_mfma(
    const float* __restrict__ in,
    const unsigned short* __restrict__ w1t, const float* __restrict__ b1,
    const unsigned short* __restrict__ w2t, const float* __restrict__ b2,
    float* __restrict__ h,
    const unsigned short* __restrict__ cf1t, float* __restrict__ xh,
    float* __restrict__ aggz, int N)
{
    __shared__ __align__(16) short a_b[16][136];
    __shared__ __align__(16) short t_b[16][136];
    const int t = threadIdx.x;
    const long r0 = (long)blockIdx.x * 16;
    #pragma unroll
    for (int j = 0; j < 2; ++j) {
        const int fi = t + j * 256;
        const int r = fi >> 5, c4 = (fi & 31) << 2;
        const long n = r0 + r;
        float4 v = make_float4(0.f, 0.f, 0.f, 0.f);
        if (n < N) v = *(const float4*)(in + n * 128 + c4);
        *(uint2*)&a_b[r][c4] = make_uint2(pk2(v.x, v.y), pk2(v.z, v.w));
    }
    __syncthreads();
    const int lane = t & 63, w = t >> 6;
    const int colL = lane & 15, quad = lane >> 4;
    const int nh = w * 32;
    {
        f32x4 acc[2];
        #pragma unroll
        for (int tt = 0; tt < 2; ++tt) acc[tt] = (f32x4){0.f, 0.f, 0.f, 0.f};
        #pragma unroll
        for (int ks = 0; ks < 4; ++ks) {
            const bfrag a = *(const bfrag*)&a_b[colL][ks * 32 + quad * 8];
            #pragma unroll
            for (int tt = 0; tt < 2; ++tt) {
                const bfrag wf = *(const bfrag*)&w1t[(long)(nh + tt * 16 + colL) * 128 + ks * 32 + quad * 8];
                acc[tt] = __builtin_amdgcn_mfma_f32_16x16x32_bf16(wf, a, acc[tt], 0, 0, 0);
            }
        }
        #pragma unroll
        for (int tt = 0; tt < 2; ++tt) {
            const int c0 = nh + tt * 16 + quad * 4;
            const float4 bv = *(const float4*)(b1 + c0);
            const float v0 = ssp_f(acc[tt][0] + bv.x);
            const float v1 = ssp_f(acc[tt][1] + bv.y);
            const float v2 = ssp_f(acc[tt][2] + bv.z);
            const float v3 = ssp_f(acc[tt][3] + bv.w);
            *(uint2*)&t_b[colL][c0] = make_uint2(pk2(v0, v1), pk2(v2, v3));
        }
    }
    __syncthreads();   // a_b reads done, t_b ready
    {
        f32x4 acc[2];
        #pragma unroll
        for (int tt = 0; tt < 2; ++tt) acc[tt] = (f32x4){0.f, 0.f, 0.f, 0.f};
        #pragma unroll
        for (int ks = 0; ks < 4; ++ks) {
            const bfrag a = *(const bfrag*)&t_b[colL][ks * 32 + quad * 8];
            #pragma unroll
            for (int tt = 0; tt < 2; ++tt) {
                const bfrag wf = *(const bfrag*)&w2t[(long)(nh + tt * 16 + colL) * 128 + ks * 32 + quad * 8];
                acc[tt] = __builtin_amdgcn_mfma_f32_16x16x32_bf16(wf, a, acc[tt], 0, 0, 0);
            }
        }
        const long node = r0 + colL;
        if (node < N) {
            float* hrow = h + node * 128;
            #pragma unroll
            for (int tt = 0; tt < 2; ++tt) {
                const int c0 = nh + tt * 16 + quad * 4;
                const float4 bv = *(const float4*)(b2 + c0);
                float4 hv = *(const float4*)(hrow + c0);
                hv.x += acc[tt][0] + bv.x;
                hv.y += acc[tt][1] + bv.y;
                hv.z += acc[tt][2] + bv.z;
                hv.w += acc[tt][3] + bv.w;
                *(float4*)(hrow + c0) = hv;
                if (CHAIN)  // bf16 image of h_new into a_b for the chained GEMM
                    *(uint2*)&a_b[colL][c0] = make_uint2(pk2(hv.x, hv.y), pk2(hv.z, hv.w));
            }
        }
    }
    if (CHAIN) {
        __syncthreads();   // a_b now holds bf16 h_new
        f32x4 acc[2];
        #pragma unroll
        for (int tt = 0; tt < 2; ++tt) acc[tt] = (f32x4){0.f, 0.f, 0.f, 0.f};
        #pragma unroll
        for (int ks = 0; ks < 4; ++ks) {
            const bfrag a = *(const bfrag*)&a_b[colL][ks * 32 + quad * 8];
            #pragma unroll
            for (int tt = 0; tt < 2; ++tt) {
                const bfrag wf = *(const bfrag*)&cf1t[(long)(nh + tt * 16 + colL) * 128 + ks * 32 + quad * 8];
                acc[tt] = __builtin_amdgcn_mfma_f32_16x16x32_bf16(wf, a, acc[tt], 0, 0, 0);
            }
        }
        const long node = r0 + colL;
        if (node < N) {
            float* orow = xh + node * 128;
            float* zrow = aggz + node * 128;
            const float4 z = make_float4(0.f, 0.f, 0.f, 0.f);
            #pragma unroll
            for (int tt = 0; tt < 2; ++tt) {
                const int c0 = nh + tt * 16 + quad * 4;
                *(float4*)(orow + c0) = make_float4(acc[tt][0], acc[tt][1], acc[tt][2], acc[tt][3]);
                *(float4*)(zrow + c0) = z;
            }
        }
    }
}

// ---------------- MFMA edge kernel v8: register segmented-scan epilogue -------
// vs R5/R7 artifact (259 us): runbuf + LDS overlay + 2 barriers REMOVED.
// Each thread's GEMM2 accumulator already holds 4 consecutive col-sorted edges
// (ebase..ebase+3); the segmented reduction runs in registers and atomics go
// straight to agg. Edge metadata (row/col/C) as int4/float4 register loads
// (tiny contiguous streams -- NOT the R6 xh burst). xh gather stays at the
// verified R5 position (after GEMM1 MFMAs).
__global__ __launch_bounds__(256, 8) void edge_mfma(
    const int* __restrict__ rowS, const int* __restrict__ colS,
    const float* __restrict__ CS, const float* __restrict__ ewS,
    const unsigned short* __restrict__ eaS,
    const unsigned short* __restrict__ w1t, const float* __restrict__ b1,
    const unsigned short* __restrict__ w2t, const float* __restrict__ b2,
    const float* __restrict__ xh, float* __restrict__ agg,
    int E, int NB, int F50, float delta, float coeff)
{
    __shared__ __align__(16) short ea_b[32][64];   // 4KB, XOR-swizzled
    __shared__ __align__(16) short t_b[32][128];   // 8KB, XOR-swizzled
    __shared__ float ew_s[32];

    const int t = threadIdx.x;
    const long p0 = (long)blockIdx.x * 32;
    const int lane = t & 63;
    const int w    = t >> 6;
    const int colL = lane & 15;
    const int quad = lane >> 4;
    const int m0   = (w & 1) * 16;
    const int ebase = m0 + quad * 4;

    // per-lane edge metadata straight to registers (contiguous, small)
    int   row_r[4], col_r[4];
    float C_r[4];
    if (p0 + 32 <= E) {
        const int4   rv = *(const int4*)&rowS[p0 + ebase];
        const int4   cv = *(const int4*)&colS[p0 + ebase];
        const float4 Cv = *(const float4*)&CS[p0 + ebase];
        row_r[0] = rv.x; row_r[1] = rv.y; row_r[2] = rv.z; row_r[3] = rv.w;
        col_r[0] = cv.x; col_r[1] = cv.y; col_r[2] = cv.z; col_r[3] = cv.w;
        C_r[0] = Cv.x; C_r[1] = Cv.y; C_r[2] = Cv.z; C_r[3] = Cv.w;
    } else {
        #pragma unroll
        for (int reg = 0; reg < 4; ++reg) {
            long p = p0 + ebase + reg;
            const long pc = (p < E) ? p : E - 1;
            row_r[reg] = rowS[pc];
            col_r[reg] = colS[pc];
            C_r[reg]   = (p < E) ? CS[pc] : 0.f;
        }
    }

    // header: every wave loads all 32 ew entries (benign same-value races).
    {
        const int t32 = t & 31;
        long p = p0 + t32; if (p >= E) p = E - 1;
        ew_s[t32] = ewS[p];
    }
    // fill ea_b (swizzled): logical short k of row e lives at k ^ ((e&7)<<3)
    for (int i = t; i < 32 * 64; i += 256) {
        const int e = i >> 6, k = i & 63;
        long p = p0 + e; if (p >= E) p = E - 1;
        unsigned short v;
        if (k < NB)        v = eaS[p * 4 + k];
        else if (k < F50) {
            float d = ew_s[e] - (float)(k - NB) * delta;
            v = f2b(__expf(coeff * d * d));
        } else             v = 0;
        ea_b[e][k ^ ((e & 7) << 3)] = (short)v;
    }
    __syncthreads();

    float xv[4][4];   // prefetched xh values, consumed in the epilogue

    // ---- GEMM1: t = ssp(ea @ w1 + b1), output bf16 to t_b (swizzled) ----
    {
        f32x4 acc[4];
        #pragma unroll
        for (int tt = 0; tt < 4; ++tt) acc[tt] = (f32x4){0.f, 0.f, 0.f, 0.f};
        const int ar  = m0 + colL;
        const int asw = (ar & 7) << 3;
        #pragma unroll
        for (int ks = 0; ks < 2; ++ks) {
            const bfrag a = *(const bfrag*)&ea_b[ar][(ks * 32 + quad * 8) ^ asw];
            #pragma unroll
            for (int tt = 0; tt < 4; ++tt) {
                const int n0 = ((w >> 1) * 4 + tt) * 16;
                const bfrag b = *(const bfrag*)&w1t[(long)(n0 + colL) * 64 + ks * 32 + quad * 8];
                acc[tt] = __builtin_amdgcn_mfma_f32_16x16x32_bf16(a, b, acc[tt], 0, 0, 0);
            }
        }
        // issue the xh gather now: latency hides under ssp epilogue + barrier
        // + GEMM2's 16 MFMAs (R5-verified placement).
        #pragma unroll
        for (int reg = 0; reg < 4; ++reg) {
            const float* xr = xh + (long)row_r[reg] * 128;
            #pragma unroll
            for (int tt = 0; tt < 4; ++tt)
                xv[reg][tt] = xr[((w >> 1) * 4 + tt) * 16 + colL];
        }
        #pragma unroll
        for (int tt = 0; tt < 4; ++tt) {
            const int n0 = ((w >> 1) * 4 + tt) * 16;
            const float bcol = b1[n0 + colL];
            #pragma unroll
            for (int reg = 0; reg < 4; ++reg) {
                const int rr = m0 + quad * 4 + reg;
                float v = ssp_f(acc[tt][reg] + bcol);
                t_b[rr][(n0 + colL) ^ ((rr & 7) << 3)] = (short)f2b(v);
            }
        }
    }
    __syncthreads();

    // ---- GEMM2: v = t @ w2 + b2; register segmented scan -> atomics ----
    {
        f32x4 acc[4];
        #pragma unroll
        for (int tt = 0; tt < 4; ++tt) acc[tt] = (f32x4){0.f, 0.f, 0.f, 0.f};
        const int ar  = m0 + colL;
        const int asw = (ar & 7) << 3;
        #pragma unroll
        for (int ks = 0; ks < 4; ++ks) {
            const bfrag a = *(const bfrag*)&t_b[ar][(ks * 32 + quad * 8) ^ asw];
            #pragma unroll
            for (int tt = 0; tt < 4; ++tt) {
                const int n0 = ((w >> 1) * 4 + tt) * 16;
                const bfrag b = *(const bfrag*)&w2t[(long)(n0 + colL) * 128 + ks * 32 + quad * 8];
                acc[tt] = __builtin_amdgcn_mfma_f32_16x16x32_bf16(a, b, acc[tt], 0, 0, 0);
            }
        }
        // epilogue: this thread's 4 edges are consecutive & col-sorted; reduce
        // same-col runs in registers, one atomic per (run, channel).
        #pragma unroll
        for (int tt = 0; tt < 4; ++tt) {
            const int cg = ((w >> 1) * 4 + tt) * 16 + colL;
            const float bcol = b2[cg];
            float run = (acc[tt][0] + bcol) * C_r[0] * xv[0][tt];
            int   cur = col_r[0];
            #pragma unroll
            for (int reg = 1; reg < 4; ++reg) {
                const float msg = (acc[tt][reg] + bcol) * C_r[reg] * xv[reg][tt];
                if (col_r[reg] != cur) {
                    atomicAdd(&agg[(long)cur * 128 + cg], run);
                    run = 0.f; cur = col_r[reg];
                }
                run += msg;
            }
            atomicAdd(&agg[(long)cur * 128 + cg], run);
        }
    }
}

// ---------------- fp32 atomic edge kernel (fallback) --------------------------
__global__ __launch_bounds__(256) void edge_atomic(
    const float* __restrict__ posf,
    const int* __restrict__ row, const int* __restrict__ col,
    const float* __restrict__ eattrf,
    const float* __restrict__ w1, const float* __restrict__ b1,
    const float* __restrict__ w2, const float* __restrict__ b2,
    const float* __restrict__ xh, float* __restrict__ agg,
    int E, int NB, int F50, float delta, float coeff)
{
    __shared__ float ea_s[32][52];
    __shared__ float t_s[32][128];
    __shared__ int   row_s[32];
    __shared__ int   col_s[32];
    __shared__ float C_s[32];
    __shared__ float ew_s[32];

    const int t = threadIdx.x;
    const long e0 = (long)blockIdx.x * 32;

    if (t < 32) {
        long e = e0 + t; if (e >= E) e = E - 1;
        const int r = row[e], c = col[e];
        row_s[t] = r; col_s[t] = c;
        float dx = posf[r*3+0] - posf[c*3+0];
        float dy = posf[r*3+1] - posf[c*3+1];
        float dz = posf[r*3+2] - posf[c*3+2];
        float ew = sqrtf(dx*dx + dy*dy + dz*dz);
        ew_s[t] = ew;
        C_s[t]  = (e0 + t < E) ? 0.5f * (cosf(ew * 0.3141592653589793f) + 1.0f) : 0.f;
        for (int q = 0; q < NB; ++q)
            ea_s[t][q] = eattrf[e * NB + q];
    }
    __syncthreads();
    {
        const int NGS = F50 - NB;
        for (int i = t; i < 32 * NGS; i += 256) {
            const int e = i / NGS, g = i - e * NGS;
            const float d = ew_s[e] - (float)g * delta;
            ea_s[e][NB + g] = __expf(coeff * d * d);
        }
    }
    __syncthreads();

    const int j = t & 31, sub = t >> 5;
    const int c4 = j * 4, eb = sub * 4;
    float acc[4][4];
    {
        const float4 bv = *(const float4*)(b1 + c4);
        #pragma unroll
        for (int i = 0; i < 4; ++i) { acc[i][0]=bv.x; acc[i][1]=bv.y; acc[i][2]=bv.z; acc[i][3]=bv.w; }
        for (int k = 0; k < F50; ++k) {
            const float4 wv = *(const float4*)(w1 + k * 128 + c4);
            #pragma unroll
            for (int i = 0; i < 4; ++i) {
                const float a = ea_s[eb + i][k];
                acc[i][0] += a * wv.x; acc[i][1] += a * wv.y;
                acc[i][2] += a * wv.z; acc[i][3] += a * wv.w;
            }
        }
        #pragma unroll
        for (int i = 0; i < 4; ++i) {
            float4 o;
            o.x = ssp_f(acc[i][0]); o.y = ssp_f(acc[i][1]);
            o.z = ssp_f(acc[i][2]); o.w = ssp_f(acc[i][3]);
            *(float4*)&t_s[eb + i][c4] = o;
        }
    }
    __syncthreads();
    {
        const float4 bv = *(const float4*)(b2 + c4);
        #pragma unroll
        for (int i = 0; i < 4; ++i) { acc[i][0]=bv.x; acc[i][1]=bv.y; acc[i][2]=bv.z; acc[i][3]=bv.w; }
        #pragma unroll 4
        for (int k = 0; k < 128; ++k) {
            const float4 wv = *(const float4*)(w2 + k * 128 + c4);
            #pragma unroll
            for (int i = 0; i < 4; ++i) {
                const float a = t_s[eb + i][k];
                acc[i][0] += a * wv.x; acc[i][1] += a * wv.y;
                acc[i][2] += a * wv.z; acc[i][3] += a * wv.w;
            }
        }
    }
    #pragma unroll
    for (int i = 0; i < 4; ++i) {
        const int e = eb + i;
        if (e0 + e >= E) continue;
        const float Ce = C_s[e];
        const float4 xv = *(const float4*)(xh + (long)row_s[e] * 128 + c4);
        float* ag = agg + (long)col_s[e] * 128 + c4;
        atomicAdd(ag + 0, acc[i][0] * Ce * xv.x);
        atomicAdd(ag + 1, acc[i][1] * Ce * xv.y);
        atomicAdd(ag + 2, acc[i][2] * Ce * xv.z);
        atomicAdd(ag + 3, acc[i][3] * Ce * xv.w);
    }
}

// ---------------- MFMA readout, 16-row tile ------------------------------------
__global__ __launch_bounds__(256) void readout_mfma(
    const float* __restrict__ h, const unsigned short* __restrict__ o1t,
    const float* __restrict__ o1b, const float* __restrict__ o2w,
    const float* __restrict__ o2b, const int* __restrict__ batch,
    float* __restrict__ accb, int N)
{
    __shared__ __align__(16) short a_b[16][136];
    __shared__ float nb[16];
    const int t = threadIdx.x;
    const long r0 = (long)blockIdx.x * 16;
    #pragma unroll
    for (int j = 0; j < 2; ++j) {
        const int fi = t + j * 256;
        const int r = fi >> 5, c4 = (fi & 31) << 2;
        const long n = r0 + r;
        float4 v = make_float4(0.f, 0.f, 0.f, 0.f);
        if (n < N) v = *(const float4*)(h + n * 128 + c4);
        *(uint2*)&a_b[r][c4] = make_uint2(pk2(v.x, v.y), pk2(v.z, v.w));
    }
    if (t < 16) nb[t] = 0.f;
    __syncthreads();
    const int lane = t & 63, w = t >> 6;
    const int colL = lane & 15, quad = lane >> 4;
    const int nh = w * 16;                  // 4 waves x 16 = 64 out1 channels
    f32x4 acc = (f32x4){0.f, 0.f, 0.f, 0.f};
    #pragma unroll
    for (int ks = 0; ks < 4; ++ks) {
        const bfrag a = *(const bfrag*)&a_b[colL][ks * 32 + quad * 8];
        const bfrag wf = *(const bfrag*)&o1t[(long)(nh + colL) * 128 + ks * 32 + quad * 8];
        acc = __builtin_amdgcn_mfma_f32_16x16x32_bf16(wf, a, acc, 0, 0, 0);
    }
    float s = 0.f;
    {
        const int c0 = nh + quad * 4;
        const float4 bv = *(const float4*)(o1b + c0);
        const float4 wv = *(const float4*)(o2w + c0);
        s += ssp_f(acc[0] + bv.x) * wv.x;
        s += ssp_f(acc[1] + bv.y) * wv.y;
        s += ssp_f(acc[2] + bv.z) * wv.z;
        s += ssp_f(acc[3] + bv.w) * wv.w;
    }
    s += __shfl_xor(s, 16);
    s += __shfl_xor(s, 32);
    if (quad == 0) atomicAdd(&nb[colL], s);
    __syncthreads();
    if (t < 16) {
        const long node = r0 + t;
        if (node < N) atomicAdd(&accb[batch[node]], nb[t] + o2b[0]);
    }
}

// ---------------- simple readout (fallback path) -------------------------------
__global__ __launch_bounds__(128) void readout_simple(
    const float* __restrict__ h,
    const float* __restrict__ o1w, const float* __restrict__ o1b,
    const float* __restrict__ o2w, const float* __restrict__ o2b,
    const int* __restrict__ batch, float* __restrict__ accb)
{
    __shared__ float hr[128];
    __shared__ float vv[64];
    const int n = blockIdx.x;
    const int t = threadIdx.x;
    hr[t] = h[(long)n * 128 + t];
    __syncthreads();
    if (t < 64) {
        float a = o1b[t];
        #pragma unroll 8
        for (int k = 0; k < 128; ++k)
            a = fmaf(hr[k], o1w[k * 64 + t], a);
        vv[t] = ssp_f(a) * o2w[t];
    }
    __syncthreads();
    if (t < 32) vv[t] += vv[t + 32];
    __syncthreads();
    if (t < 16) vv[t] += vv[t + 16];
    __syncthreads();
    if (t < 8)  vv[t] += vv[t + 8];
    __syncthreads();
    if (t < 4)  vv[t] += vv[t + 4];
    __syncthreads();
    if (t < 2)  vv[t] += vv[t + 2];
    __syncthreads();
    if (t == 0) atomicAdd(&accb[batch[n]], vv[0] + vv[1] + o2b[0]);
}

// output is FLOAT32 (verified round 11)
__global__ void finalize_kernel(const float* __restrict__ accb,
                                float* __restrict__ out, int B)
{
    int t = blockIdx.x * 256 + threadIdx.x;
    if (t < B) out[t] = accb[t];
}

// ---------------- launch -------------------------------------------------------
extern "C" void kernel_launch(void* const* d_in, const int* in_sizes, int n_in,
                              void* d_out, int out_size, void* d_ws, size_t ws_size,
                              hipStream_t stream)
{
    const int N   = in_sizes[0];
    const int E   = in_sizes[3] / 2;
    const int B   = out_size;
    const int H   = 128;
    const int L   = in_sizes[7] / H;
    const int NB  = in_sizes[4] / E;
    const int F50 = in_sizes[6] / (L * H);
    const int NGS = F50 - NB;
    const float delta = 10.0f / (float)(NGS - 1);
    const float coeff = -0.5f / (delta * delta);

    const int fidx[16] = {1, 4, 5, 6, 7, 8, 9, 10, 11, 12, 13, 14, 15, 16, 17, 18};
    Cvt16 cv;
    cv.off[0] = 0;
    for (int i = 0; i < 16; ++i) {
        cv.src[i] = d_in[fidx[i]];
        cv.off[i + 1] = cv.off[i] + in_sizes[fidx[i]];
    }
    const long ftot = cv.off[16];

    float* F = (float*)d_ws;
    long base = (ftot + 3) & ~3L;
    float* h    = F + base;
    float* xh   = h + (long)N * H;
    float* agg  = xh + (long)N * H;
    float* accb = agg + (long)N * H;
    int*   flag  = (int*)(accb + ((B + 3) & ~3));
    int*   iflag = flag + 1;
    int*   zi     = flag + 4;
    int*   batchi = zi + N;
    int*   eidxi  = batchi + N;
    int*   count  = eidxi + 2 * E;
    int*   rowptr = count + N;
    int*   next   = rowptr + N + 1;
    int*   rowS   = next + N;
    int*   colS   = rowS + E;
    float* CS     = (float*)(colS + E);
    float* ewS    = CS + E;
    unsigned short* eaS = (unsigned short*)(ewS + E);      // 4E ushorts
    unsigned short* w1t = eaS + 4L * E;                    // L*128*64
    unsigned short* w2t = w1t + (long)L * 128 * 64;        // L*128*128
    unsigned short* nwt = w2t + (long)L * 128 * 128;       // 3L*128*128
    unsigned short* o1t = nwt + 3L * L * 128 * 128;        // 64*128
    long used_bytes = (long)((char*)(o1t + 64 * 128) - (char*)d_ws);
    const bool use_fast = (used_bytes <= (long)ws_size) && (F50 <= 64) && (NB <= 4);

    sniff_kernel<<<1, 256, 0, stream>>>((const unsigned int*)d_in[5], flag);
    sniff_int_kernel<<<1, 128, 0, stream>>>((const unsigned int*)d_in[0], iflag);

    convert_fused_kernel<<<(int)((ftot + 255) / 256), 256, 0, stream>>>(cv, F, ftot, flag);
    convert_int_kernel<<<(N + 255) / 256, 256, 0, stream>>>(d_in[0], zi, N, iflag);
    convert_int_kernel<<<(N + 255) / 256, 256, 0, stream>>>(d_in[2], batchi, N, iflag);
    convert_int_kernel<<<(2 * E + 255) / 256, 256, 0, stream>>>(d_in[3], eidxi, 2 * E, iflag);

    const float* posf   = F + cv.off[0];
    const float* eattrf = F + cv.off[1];
    const float* embf   = F + cv.off[2];
    const float* w1   = F + cv.off[3];  const float* b1   = F + cv.off[4];
    const float* w2   = F + cv.off[5];  const float* b2   = F + cv.off[6];
    const float* cf1  = F + cv.off[7];  const float* cf2  = F + cv.off[8];
    const float* cf2b = F + cv.off[9];  const float* lin  = F + cv.off[10];
    const float* linb = F + cv.off[11]; const float* o1   = F + cv.off[12];
    const float* o1b  = F + cv.off[13]; const float* o2   = F + cv.off[14];
    const float* o2b  = F + cv.off[15];

    if (use_fast) {
        zero_int_kernel<<<(N + 255) / 256, 256, 0, stream>>>(count, N);
        hist_kernel<<<(E + 255) / 256, 256, 0, stream>>>(eidxi + E, count, E);
        scan_kernel<<<1, 256, 0, stream>>>(count, rowptr, next, N);
        prep_scatter_kernel<<<(E + 255) / 256, 256, 0, stream>>>(
            posf, eidxi, eidxi + E, eattrf, next, rowS, colS, CS, ewS, eaS, E, NB);
        const int wt_total = L * 8192 + L * 16384 + 3 * L * 16384 + 8192;
        wtrans_all_kernel<<<(wt_total + 255) / 256, 256, 0, stream>>>(
            w1, w2, cf1, cf2, lin, o1, w1t, w2t, nwt, o1t, L, F50, wt_total);
    }

    hipMemsetAsync(accb, 0, (size_t)B * sizeof(float), stream);

    const int ngemm16 = (N + 15) / 16;
    const int nedge   = (E + 31) / 32;
    if (use_fast) {
        node_gemm1_embed_mfma<<<ngemm16, 256, 0, stream>>>(
            zi, embf, nwt + 0, h, xh, agg, N);
        for (int l = 0; l < L; ++l) {
            edge_mfma<<<nedge, 256, 0, stream>>>(
                rowS, colS, CS, ewS, eaS,
                w1t + (long)l * 128 * 64, b1 + (long)l * H,
                w2t + (long)l * 128 * 128, b2 + (long)l * H,
                xh, agg, E, NB, F50, delta, coeff);
            if (l < L - 1) {
                node_gemm23_mfma<1><<<ngemm16, 256, 0, stream>>>(
                    agg, nwt + (long)(l * 3 + 1) * 16384, cf2b + (long)l * H,
                    nwt + (long)(l * 3 + 2) * 16384, linb + (long)l * H, h,
                    nwt + (long)((l + 1) * 3 + 0) * 16384, xh, agg, N);
            } else {
                node_gemm23_mfma<0><<<ngemm16, 256, 0, stream>>>(
                    agg, nwt + (long)(l * 3 + 1) * 16384, cf2b + (long)l * H,
                    nwt + (long)(l * 3 + 2) * 16384, linb + (long)l * H, h,
                    nullptr, nullptr, nullptr, N);
            }
        }
        readout_mfma<<<ngemm16, 256, 0, stream>>>(h, o1t, o1b, o2, o2b, batchi, accb, N);
    } else {
        embed_kernel<<<(N * H + 255) / 256, 256, 0, stream>>>(zi, embf, h, N * H);
        const int ngemm32 = (N + 31) / 32;
        for (int l = 0; l < L; ++l) {
            hipMemsetAsync(agg, 0, (size_t)N * H * sizeof(float), stream);
            node_gemm_tiled<0><<<ngemm32, 256, 0, stream>>>(h, cf1 + (long)l * H * H, nullptr, xh, N);
            edge_atomic<<<nedge, 256, 0, stream>>>(
                posf, eidxi, eidxi + E, eattrf,
                w1 + (long)l * F50 * H, b1 + (long)l * H,
                w2 + (long)l * H * H,  b2 + (long)l * H,
                xh, agg, E, NB, F50, delta, coeff);
            node_gemm_tiled<1><<<ngemm32, 256, 0, stream>>>(agg, cf2 + (long)l * H * H, cf2b + (long)l * H, xh, N);
            node_gemm_tiled<2><<<ngemm32, 256, 0, stream>>>(xh, lin + (long)l * H * H, linb + (long)l * H, h, N);
        }
        readout_simple<<<N, 128, 0, stream>>>(h, o1, o1b, o2, o2b, batchi, accb);
    }
    finalize_kernel<<<(B + 255) / 256, 256, 0, stream>>>(accb, (float*)d_out, B);
}

// Round 9
// 1264.707 us; speedup vs baseline: 1.2492x; 1.2492x over previous
//
#include <hip/hip_runtime.h>
#include <hip/hip_bf16.h>

typedef __attribute__((ext_vector_type(8))) short bfrag;
typedef __attribute__((ext_vector_type(4))) float f32x4;

// fast shifted softplus: __logf/__expf intrinsics (rel err ~2^-21, threshold 2.3e-2)
__device__ __forceinline__ float ssp_f(float x) {
    return fmaxf(x, 0.f) + __logf(1.f + __expf(-fabsf(x))) - 0.6931471805599453f;
}

__device__ __forceinline__ unsigned short f2b(float x) {
    __hip_bfloat16 h = __float2bfloat16(x);
    return *(unsigned short*)&h;
}

__device__ __forceinline__ unsigned int pk2(float a, float b) {
    __hip_bfloat162 h2 = __float22bfloat162_rn(make_float2(a, b));
    return *(unsigned int*)&h2;
}

// ---------------- float dtype sniffer ----------------------------------------
__global__ void sniff_kernel(const unsigned int* __restrict__ raw, int* __restrict__ flag)
{
    __shared__ int cnt[256];
    const int t = threadIdx.x;
    unsigned int w = raw[t];
    unsigned int e = (w >> 7) & 0xFFu;
    cnt[t] = (e >= 100u && e <= 135u) ? 1 : 0;
    __syncthreads();
    for (int s = 128; s > 0; s >>= 1) {
        if (t < s) cnt[t] += cnt[t + s];
        __syncthreads();
    }
    if (t == 0) *flag = (cnt[0] >= 160) ? 1 : 0;   // 1 = floats are bf16
}

// ---------------- int width sniffer -------------------------------------------
__global__ void sniff_int_kernel(const unsigned int* __restrict__ z, int* __restrict__ iflag)
{
    __shared__ int cnt[128];
    const int t = threadIdx.x;
    cnt[t] = (z[2 * t + 1] == 0u) ? 1 : 0;
    __syncthreads();
    for (int s = 64; s > 0; s >>= 1) {
        if (t < s) cnt[t] += cnt[t + s];
        __syncthreads();
    }
    if (t == 0) *iflag = (cnt[0] >= 126) ? 1 : 0;  // 1 = ints are int64
}

// ---------------- fused convert of all 16 float tensors -----------------------
struct Cvt16 {
    const void* src[16];
    long off[17];
};

__global__ __launch_bounds__(256) void convert_fused_kernel(
    Cvt16 args, float* __restrict__ F, long total, const int* __restrict__ flag)
{
    long i = (long)blockIdx.x * 256 + threadIdx.x;
    if (i >= total) return;
    int lo = 0, hi = 16;
    while (hi - lo > 1) {
        int mid = (lo + hi) >> 1;
        if (i >= args.off[mid]) lo = mid; else hi = mid;
    }
    long loc = i - args.off[lo];
    if (*flag) F[i] = __bfloat162float(((const __hip_bfloat16*)args.src[lo])[loc]);
    else       F[i] = ((const float*)args.src[lo])[loc];
}

__global__ __launch_bounds__(256) void convert_int_kernel(
    const void* __restrict__ src, int* __restrict__ dst, int n,
    const int* __restrict__ iflag)
{
    int i = blockIdx.x * 256 + threadIdx.x;
    if (i >= n) return;
    if (*iflag) dst[i] = (int)(((const long long*)src)[i]);
    else        dst[i] = ((const int*)src)[i];
}

// ---------------- node embedding gather (fallback path) ------------------------
__global__ __launch_bounds__(256) void embed_kernel(
    const int* __restrict__ z, const float* __restrict__ embf,
    float* __restrict__ h, int NH)
{
    int idx = blockIdx.x * 256 + threadIdx.x;
    if (idx >= NH) return;
    h[idx] = embf[z[idx >> 7] * 128 + (idx & 127)];
}

// ---------------- CSR build ----------------------------------------------------
__global__ __launch_bounds__(256) void zero_int_kernel(int* p, int n)
{
    int i = blockIdx.x * 256 + threadIdx.x;
    if (i < n) p[i] = 0;
}

__global__ __launch_bounds__(256) void hist_kernel(const int* __restrict__ col,
                                                   int* __restrict__ count, int E)
{
    int e = blockIdx.x * 256 + threadIdx.x;
    if (e < E) atomicAdd(&count[col[e]], 1);
}

__global__ __launch_bounds__(256) void scan_kernel(const int* __restrict__ count,
                                                   int* __restrict__ rowptr,
                                                   int* __restrict__ next, int N)
{
    __shared__ int part[256];
    const int t = threadIdx.x;
    const int chunk = (N + 255) / 256;
    const int lo = t * chunk, hi = min(lo + chunk, N);
    int s = 0;
    for (int i = lo; i < hi; ++i) s += count[i];
    part[t] = s;
    __syncthreads();
    if (t == 0) {
        int run = 0;
        for (int i = 0; i < 256; ++i) { int v = part[i]; part[i] = run; run += v; }
        rowptr[N] = run;
    }
    __syncthreads();
    int run = part[t];
    for (int i = lo; i < hi; ++i) {
        rowptr[i] = run; next[i] = run;
        run += count[i];
    }
}

// fused slot+perm+prep: scatter edge data directly into col-sorted order
__global__ __launch_bounds__(256) void prep_scatter_kernel(
    const float* __restrict__ posf, const int* __restrict__ row,
    const int* __restrict__ col, const float* __restrict__ eattrf,
    int* __restrict__ next,
    int* __restrict__ rowS, int* __restrict__ colS,
    float* __restrict__ CS, float* __restrict__ ewS,
    unsigned short* __restrict__ eaS, int E, int NB)
{
    int e = blockIdx.x * 256 + threadIdx.x;
    if (e >= E) return;
    const int r = row[e], c = col[e];
    const int p = atomicAdd(&next[c], 1);
    float dx = posf[r*3+0] - posf[c*3+0];
    float dy = posf[r*3+1] - posf[c*3+1];
    float dz = posf[r*3+2] - posf[c*3+2];
    float ew = sqrtf(dx*dx + dy*dy + dz*dz);
    rowS[p] = r; colS[p] = c; ewS[p] = ew;
    CS[p] = 0.5f * (cosf(ew * 0.3141592653589793f) + 1.0f);
    unsigned short* o = eaS + (long)p * 4;
    for (int q = 0; q < 4; ++q)
        o[q] = (q < NB) ? f2b(eattrf[(long)e * NB + q]) : (unsigned short)0;
}

// ---------------- fused weight transpose (fast path): all tensors in one ------
__global__ __launch_bounds__(256) void wtrans_all_kernel(
    const float* __restrict__ w1, const float* __restrict__ w2,
    const float* __restrict__ cf1, const float* __restrict__ cf2,
    const float* __restrict__ lin, const float* __restrict__ o1,
    unsigned short* __restrict__ w1t, unsigned short* __restrict__ w2t,
    unsigned short* __restrict__ nwt, unsigned short* __restrict__ o1t,
    int L, int F50, int total)
{
    int idx = blockIdx.x * 256 + threadIdx.x;
    if (idx >= total) return;
    const int A  = L * 8192;
    const int Bq = L * 16384;
    const int Cq = 3 * L * 16384;
    if (idx < A) {
        const int l = idx >> 13, local = idx & 8191;
        const int n = local >> 6, k = local & 63;
        w1t[idx] = (k < F50) ? f2b(w1[(long)l * F50 * 128 + k * 128 + n]) : (unsigned short)0;
    } else if (idx < A + Bq) {
        const int j = idx - A;
        const int l = j >> 14, local = j & 16383;
        const int n = local >> 7, k = local & 127;
        w2t[j] = f2b(w2[(long)l * 16384 + k * 128 + n]);
    } else if (idx < A + Bq + Cq) {
        const int j = idx - A - Bq;
        const int m = j >> 14;
        const int fam = m % 3, l = m / 3;
        const int local = j & 16383;
        const int n = local >> 7, k = local & 127;
        const float* src = (fam == 0 ? cf1 : fam == 1 ? cf2 : lin) + (long)l * 16384;
        nwt[j] = f2b(src[k * 128 + n]);
    } else {
        const int j = idx - A - Bq - Cq;
        const int n = j >> 7, k = j & 127;
        o1t[j] = f2b(o1[k * 64 + n]);
    }
}

// ---------------- fp32 node GEMM (fallback path only) -------------------------
template<int MODE>
__global__ __launch_bounds__(256) void node_gemm_tiled(
    const float* __restrict__ in, const float* __restrict__ W,
    const float* __restrict__ bias, float* __restrict__ out, int N)
{
    __shared__ float in_s[32][128];
    const int t = threadIdx.x;
    const long n0 = (long)blockIdx.x * 32;
    for (int i = t; i < 32 * 128; i += 256) {
        long n = n0 + (i >> 7);
        in_s[i >> 7][i & 127] = (n < N) ? in[n * 128 + (i & 127)] : 0.f;
    }
    __syncthreads();
    const int j = t & 31, sub = t >> 5;
    const int c4 = j * 4, rb = sub * 4;
    float acc[4][4];
    float4 bv = make_float4(0.f, 0.f, 0.f, 0.f);
    if (MODE != 0) bv = *(const float4*)(bias + c4);
    #pragma unroll
    for (int i = 0; i < 4; ++i) { acc[i][0]=bv.x; acc[i][1]=bv.y; acc[i][2]=bv.z; acc[i][3]=bv.w; }
    #pragma unroll 4
    for (int k = 0; k < 128; ++k) {
        const float4 wv = *(const float4*)(W + k * 128 + c4);
        #pragma unroll
        for (int i = 0; i < 4; ++i) {
            const float a = in_s[rb + i][k];
            acc[i][0] += a * wv.x; acc[i][1] += a * wv.y;
            acc[i][2] += a * wv.z; acc[i][3] += a * wv.w;
        }
    }
    #pragma unroll
    for (int i = 0; i < 4; ++i) {
        long n = n0 + rb + i;
        if (n >= N) continue;
        float4 o;
        if (MODE == 1) {
            o.x = ssp_f(acc[i][0]); o.y = ssp_f(acc[i][1]);
            o.z = ssp_f(acc[i][2]); o.w = ssp_f(acc[i][3]);
        } else {
            o.x = acc[i][0]; o.y = acc[i][1]; o.z = acc[i][2]; o.w = acc[i][3];
        }
        if (MODE == 2) {
            float4 p = *(const float4*)(out + n * 128 + c4);
            o.x += p.x; o.y += p.y; o.z += p.z; o.w += p.w;
        }
        *(float4*)(out + n * 128 + c4) = o;
    }
}

// ------- MFMA node GEMM, 16-row tile: xh = emb[z] @ cf1, writes h, zeroes agg --
__global__ __launch_bounds__(256) void node_gemm1_embed_mfma(
    const int* __restrict__ zi, const float* __restrict__ embf,
    const unsigned short* __restrict__ wt,
    float* __restrict__ h, float* __restrict__ out, float* __restrict__ aggz, int N)
{
    __shared__ __align__(16) short a_b[16][136];
    const int t = threadIdx.x;
    const long r0 = (long)blockIdx.x * 16;
    const float4 z4 = make_float4(0.f, 0.f, 0.f, 0.f);
    #pragma unroll
    for (int j = 0; j < 2; ++j) {
        const int fi = t + j * 256;          // float4 index 0..511
        const int r = fi >> 5, c4 = (fi & 31) << 2;
        const long n = r0 + r;
        float4 v = z4;
        if (n < N) {
            v = *(const float4*)(embf + (long)zi[n] * 128 + c4);
            *(float4*)(h + n * 128 + c4) = v;       // materialize h = emb[z]
            *(float4*)(aggz + n * 128 + c4) = z4;   // zero agg slice
        }
        *(uint2*)&a_b[r][c4] = make_uint2(pk2(v.x, v.y), pk2(v.z, v.w));
    }
    __syncthreads();
    const int lane = t & 63, w = t >> 6;
    const int colL = lane & 15, quad = lane >> 4;
    const int nh = w * 32;
    f32x4 acc[2];
    #pragma unroll
    for (int tt = 0; tt < 2; ++tt) acc[tt] = (f32x4){0.f, 0.f, 0.f, 0.f};
    #pragma unroll
    for (int ks = 0; ks < 4; ++ks) {
        const bfrag a = *(const bfrag*)&a_b[colL][ks * 32 + quad * 8];
        #pragma unroll
        for (int tt = 0; tt < 2; ++tt) {
            const bfrag wf = *(const bfrag*)&wt[(long)(nh + tt * 16 + colL) * 128 + ks * 32 + quad * 8];
            acc[tt] = __builtin_amdgcn_mfma_f32_16x16x32_bf16(wf, a, acc[tt], 0, 0, 0);
        }
    }
    const long node = r0 + colL;
    if (node < N) {
        float* orow = out + node * 128;
        #pragma unroll
        for (int tt = 0; tt < 2; ++tt) {
            const int c0 = nh + tt * 16 + quad * 4;
            *(float4*)(orow + c0) = make_float4(acc[tt][0], acc[tt][1], acc[tt][2], acc[tt][3]);
        }
    }
}

// ------- MFMA fused node block, 16-row tile ------------------------------------
template<int CHAIN>
__global__ __launch_bounds__(256) void node_gemm23_mfma(
    const float* __restrict__ in,
    const unsigned short* __restrict__ w1t, const float* __restrict__ b1,
    const unsigned short* __restrict__ w2t, const float* __restrict__ b2,
    float* __restrict__ h,
    const unsigned short* __restrict__ cf1t, float* __restrict__ xh,
    float* __restrict__ aggz, int N)
{
    __shared__ __align__(16) short a_b[16][136];
    __shared__ __align__(16) short t_b[16][136];
    const int t = threadIdx.x;
    const long r0 = (long)blockIdx.x * 16;
    #pragma unroll
    for (int j = 0; j < 2; ++j) {
        const int fi = t + j * 256;
        const int r = fi >> 5, c4 = (fi & 31) << 2;
        const long n = r0 + r;
        float4 v = make_float4(0.f, 0.f, 0.f, 0.f);
        if (n < N) v = *(const float4*)(in + n * 128 + c4);
        *(uint2*)&a_b[r][c4] = make_uint2(pk2(v.x, v.y), pk2(v.z, v.w));
    }
    __syncthreads();
    const int lane = t & 63, w = t >> 6;
    const int colL = lane & 15, quad = lane >> 4;
    const int nh = w * 32;
    {
        f32x4 acc[2];
        #pragma unroll
        for (int tt = 0; tt < 2; ++tt) acc[tt] = (f32x4){0.f, 0.f, 0.f, 0.f};
        #pragma unroll
        for (int ks = 0; ks < 4; ++ks) {
            const bfrag a = *(const bfrag*)&a_b[colL][ks * 32 + quad * 8];
            #pragma unroll
            for (int tt = 0; tt < 2; ++tt) {
                const bfrag wf = *(const bfrag*)&w1t[(long)(nh + tt * 16 + colL) * 128 + ks * 32 + quad * 8];
                acc[tt] = __builtin_amdgcn_mfma_f32_16x16x32_bf16(wf, a, acc[tt], 0, 0, 0);
            }
        }
        #pragma unroll
        for (int tt = 0; tt < 2; ++tt) {
            const int c0 = nh + tt * 16 + quad * 4;
            const float4 bv = *(const float4*)(b1 + c0);
            const float v0 = ssp_f(acc[tt][0] + bv.x);
            const float v1 = ssp_f(acc[tt][1] + bv.y);
            const float v2 = ssp_f(acc[tt][2] + bv.z);
            const float v3 = ssp_f(acc[tt][3] + bv.w);
            *(uint2*)&t_b[colL][c0] = make_uint2(pk2(v0, v1), pk2(v2, v3));
        }
    }
    __syncthreads();   // a_b reads done, t_b ready
    {
        f32x4 acc[2];
        #pragma unroll
        for (int tt = 0; tt < 2; ++tt) acc[tt] = (f32x4){0.f, 0.f, 0.f, 0.f};
        #pragma unroll
        for (int ks = 0; ks < 4; ++ks) {
            const bfrag a = *(const bfrag*)&t_b[colL][ks * 32 + quad * 8];
            #pragma unroll
            for (int tt = 0; tt < 2; ++tt) {
                const bfrag wf = *(const bfrag*)&w2t[(long)(nh + tt * 16 + colL) * 128 + ks * 32 + quad * 8];
                acc[tt] = __builtin_amdgcn_mfma_f32_16x16x32_bf16(wf, a, acc[tt], 0, 0, 0);
            }
        }
        const long node = r0 + colL;
        if (node < N) {
            float* hrow = h + node * 128;
            #pragma unroll
            for (int tt = 0; tt < 2; ++tt) {
                const int c0 = nh + tt * 16 + quad * 4;
                const float4 bv = *(const float4*)(b2 + c0);
                float4 hv = *(const float4*)(hrow + c0);
                hv.x += acc[tt][0] + bv.x;
                hv.y += acc[tt][1] + bv.y;
                hv.z += acc[tt][2] + bv.z;
                hv.w += acc[tt][3] + bv.w;
                *(float4*)(hrow + c0) = hv;
                if (CHAIN)  // bf16 image of h_new into a_b for the chained GEMM
                    *(uint2*)&a_b[colL][c0] = make_uint2(pk2(hv.x, hv.y), pk2(hv.z, hv.w));
            }
        }
    }
    if (CHAIN) {
        __syncthreads();   // a_b now holds bf16 h_new
        f32x4 acc[2];
        #pragma unroll
        for (int tt = 0; tt < 2; ++tt) acc[tt] = (f32x4){0.f, 0.f, 0.f, 0.f};
        #pragma unroll
        for (int ks = 0; ks < 4; ++ks) {
            const bfrag a = *(const bfrag*)&a_b[colL][ks * 32 + quad * 8];
            #pragma unroll
            for (int tt = 0; tt < 2; ++tt) {
                const bfrag wf = *(const bfrag*)&cf1t[(long)(nh + tt * 16 + colL) * 128 + ks * 32 + quad * 8];
                acc[tt] = __builtin_amdgcn_mfma_f32_16x16x32_bf16(wf, a, acc[tt], 0, 0, 0);
            }
        }
        const long node = r0 + colL;
        if (node < N) {
            float* orow = xh + node * 128;
            float* zrow = aggz + node * 128;
            const float4 z = make_float4(0.f, 0.f, 0.f, 0.f);
            #pragma unroll
            for (int tt = 0; tt < 2; ++tt) {
                const int c0 = nh + tt * 16 + quad * 4;
                *(float4*)(orow + c0) = make_float4(acc[tt][0], acc[tt][1], acc[tt][2], acc[tt][3]);
                *(float4*)(zrow + c0) = z;
            }
        }
    }
}

// ---------------- MFMA edge kernel — R7 artifact (259 us) + XCD swizzle -------
// Structure identical to the measured-259us R7 kernel (runbuf overlay + LDS
// segmented scan = minimum atomic count; R8 proved dropping the scan costs
// 4x atomics -> +100us). NEW: XCD-aware blockIdx swizzle -- edges are
// col-sorted, so consecutive blocks hit the same agg lines; giving each XCD a
// contiguous block chunk keeps those atomic lines in ONE non-coherent L2.
__global__ __launch_bounds__(256, 8) void edge_mfma(
    const int* __restrict__ rowS, const int* __restrict__ colS,
    const float* __restrict__ CS, const float* __restrict__ ewS,
    const unsigned short* __restrict__ eaS,
    const unsigned short* __restrict__ w1t, const float* __restrict__ b1,
    const unsigned short* __restrict__ w2t, const float* __restrict__ b2,
    const float* __restrict__ xh, float* __restrict__ agg,
    int E, int NB, int F50, float delta, float coeff)
{
    // phase A: ea_b[32][64] shorts (4KB @0) + t_b[32][128] shorts (8KB @4096)
    // phase B: runbuf[32][132] floats (16896B @0) -- overlays phase A
    __shared__ __align__(16) char smem[32 * 132 * 4];
    short (*ea_b)[64]    = (short(*)[64])smem;
    short (*t_b)[128]    = (short(*)[128])(smem + 4096);
    float (*runbuf)[132] = (float(*)[132])smem;
    __shared__ int   row_s[32];
    __shared__ int   col_s[32];
    __shared__ float C_s[32];
    __shared__ float ew_s[32];

    const int t = threadIdx.x;
    // XCD-aware swizzle (bijective when nwg % 8 == 0, else identity)
    const int nwg = gridDim.x;
    int bid = blockIdx.x;
    if ((nwg & 7) == 0) bid = (bid & 7) * (nwg >> 3) + (bid >> 3);
    const long p0 = (long)bid * 32;

    // header: every wave loads all 32 entries (benign same-value races) so no
    // cross-wave dependency -> no barrier needed before staging.
    {
        const int t32 = t & 31;
        long p = p0 + t32; if (p >= E) p = E - 1;
        row_s[t32] = rowS[p];
        col_s[t32] = colS[p];
        C_s[t32]   = (p0 + t32 < E) ? CS[p] : 0.f;
        ew_s[t32]  = ewS[p];
    }
    // fill ea_b (swizzled): logical short k of row e lives at k ^ ((e&7)<<3)
    for (int i = t; i < 32 * 64; i += 256) {
        const int e = i >> 6, k = i & 63;
        long p = p0 + e; if (p >= E) p = E - 1;
        unsigned short v;
        if (k < NB)        v = eaS[p * 4 + k];
        else if (k < F50) {
            float d = ew_s[e] - (float)(k - NB) * delta;
            v = f2b(__expf(coeff * d * d));
        } else             v = 0;
        ea_b[e][k ^ ((e & 7) << 3)] = (short)v;
    }
    __syncthreads();

    const int lane = t & 63;
    const int w    = t >> 6;
    const int colL = lane & 15;
    const int quad = lane >> 4;
    const int m0   = (w & 1) * 16;
    const int ebase = m0 + quad * 4;

    float xv[4][4];   // prefetched xh values, consumed in GEMM2 epilogue

    // ---- GEMM1: t = ssp(ea @ w1 + b1), output bf16 to t_b (swizzled) ----
    {
        f32x4 acc[4];
        #pragma unroll
        for (int tt = 0; tt < 4; ++tt) acc[tt] = (f32x4){0.f, 0.f, 0.f, 0.f};
        const int ar  = m0 + colL;
        const int asw = (ar & 7) << 3;
        #pragma unroll
        for (int ks = 0; ks < 2; ++ks) {
            const bfrag a = *(const bfrag*)&ea_b[ar][(ks * 32 + quad * 8) ^ asw];
            #pragma unroll
            for (int tt = 0; tt < 4; ++tt) {
                const int n0 = ((w >> 1) * 4 + tt) * 16;
                const bfrag b = *(const bfrag*)&w1t[(long)(n0 + colL) * 64 + ks * 32 + quad * 8];
                acc[tt] = __builtin_amdgcn_mfma_f32_16x16x32_bf16(a, b, acc[tt], 0, 0, 0);
            }
        }
        // issue the xh gather now: latency hides under ssp epilogue + barrier
        // + GEMM2's 16 MFMAs (R5-verified placement).
        #pragma unroll
        for (int reg = 0; reg < 4; ++reg) {
            const float* xr = xh + (long)row_s[ebase + reg] * 128;
            #pragma unroll
            for (int tt = 0; tt < 4; ++tt)
                xv[reg][tt] = xr[((w >> 1) * 4 + tt) * 16 + colL];
        }
        #pragma unroll
        for (int tt = 0; tt < 4; ++tt) {
            const int n0 = ((w >> 1) * 4 + tt) * 16;
            const float bcol = b1[n0 + colL];
            #pragma unroll
            for (int reg = 0; reg < 4; ++reg) {
                const int rr = m0 + quad * 4 + reg;
                float v = ssp_f(acc[tt][reg] + bcol);
                t_b[rr][(n0 + colL) ^ ((rr & 7) << 3)] = (short)f2b(v);
            }
        }
    }
    __syncthreads();

    // ---- GEMM2: v = t @ w2 + b2, then v * C * xv into runbuf ----
    {
        f32x4 acc[4];
        #pragma unroll
        for (int tt = 0; tt < 4; ++tt) acc[tt] = (f32x4){0.f, 0.f, 0.f, 0.f};
        const int ar  = m0 + colL;
        const int asw = (ar & 7) << 3;
        #pragma unroll
        for (int ks = 0; ks < 4; ++ks) {
            const bfrag a = *(const bfrag*)&t_b[ar][(ks * 32 + quad * 8) ^ asw];
            #pragma unroll
            for (int tt = 0; tt < 4; ++tt) {
                const int n0 = ((w >> 1) * 4 + tt) * 16;
                const bfrag b = *(const bfrag*)&w2t[(long)(n0 + colL) * 128 + ks * 32 + quad * 8];
                acc[tt] = __builtin_amdgcn_mfma_f32_16x16x32_bf16(a, b, acc[tt], 0, 0, 0);
            }
        }
        // all waves must be done reading t_b before runbuf overlays it
        __syncthreads();
        #pragma unroll
        for (int tt = 0; tt < 4; ++tt) {
            const int n0 = ((w >> 1) * 4 + tt) * 16;
            const int cg = n0 + colL;
            const float bcol = b2[cg];
            #pragma unroll
            for (int reg = 0; reg < 4; ++reg) {
                const int e = ebase + reg;
                const float v = acc[tt][reg] + bcol;
                runbuf[e][cg] = v * C_s[e] * xv[reg][tt];
            }
        }
    }
    __syncthreads();

    // ---- segmented scan over col-sorted edges: 128 threads x 2 halves ----
    {
        const int cc   = t & 127;
        const int e0h  = (t >> 7) * 16;
        float a     = runbuf[e0h][cc];
        int  curcol = col_s[e0h];
        #pragma unroll 4
        for (int e = e0h + 1; e < e0h + 16; ++e) {
            const int c2 = col_s[e];
            if (c2 != curcol) {
                atomicAdd(&agg[(long)curcol * 128 + cc], a);
                a = 0.f; curcol = c2;
            }
            a += runbuf[e][cc];
        }
        atomicAdd(&agg[(long)curcol * 128 + cc], a);
    }
}

// ---------------- fp32 atomic edge kernel (fallback) --------------------------
__global__ __launch_bounds__(256) void edge_atomic(
    const float* __restrict__ posf,
    const int* __restrict__ row, const int* __restrict__ col,
    const float* __restrict__ eattrf,
    const float* __restrict__ w1, const float* __restrict__ b1,
    const float* __restrict__ w2, const float* __restrict__ b2,
    const float* __restrict__ xh, float* __restrict__ agg,
    int E, int NB, int F50, float delta, float coeff)
{
    __shared__ float ea_s[32][52];
    __shared__ float t_s[32][128];
    __shared__ int   row_s[32];
    __shared__ int   col_s[32];
    __shared__ float C_s[32];
    __shared__ float ew_s[32];

    const int t = threadIdx.x;
    const long e0 = (long)blockIdx.x * 32;

    if (t < 32) {
        long e = e0 + t; if (e >= E) e = E - 1;
        const int r = row[e], c = col[e];
        row_s[t] = r; col_s[t] = c;
        float dx = posf[r*3+0] - posf[c*3+0];
        float dy = posf[r*3+1] - posf[c*3+1];
        float dz = posf[r*3+2] - posf[c*3+2];
        float ew = sqrtf(dx*dx + dy*dy + dz*dz);
        ew_s[t] = ew;
        C_s[t]  = (e0 + t < E) ? 0.5f * (cosf(ew * 0.3141592653589793f) + 1.0f) : 0.f;
        for (int q = 0; q < NB; ++q)
            ea_s[t][q] = eattrf[e * NB + q];
    }
    __syncthreads();
    {
        const int NGS = F50 - NB;
        for (int i = t; i < 32 * NGS; i += 256) {
            const int e = i / NGS, g = i - e * NGS;
            const float d = ew_s[e] - (float)g * delta;
            ea_s[e][NB + g] = __expf(coeff * d * d);
        }
    }
    __syncthreads();

    const int j = t & 31, sub = t >> 5;
    const int c4 = j * 4, eb = sub * 4;
    float acc[4][4];
    {
        const float4 bv = *(const float4*)(b1 + c4);
        #pragma unroll
        for (int i = 0; i < 4; ++i) { acc[i][0]=bv.x; acc[i][1]=bv.y; acc[i][2]=bv.z; acc[i][3]=bv.w; }
        for (int k = 0; k < F50; ++k) {
            const float4 wv = *(const float4*)(w1 + k * 128 + c4);
            #pragma unroll
            for (int i = 0; i < 4; ++i) {
                const float a = ea_s[eb + i][k];
                acc[i][0] += a * wv.x; acc[i][1] += a * wv.y;
                acc[i][2] += a * wv.z; acc[i][3] += a * wv.w;
            }
        }
        #pragma unroll
        for (int i = 0; i < 4; ++i) {
            float4 o;
            o.x = ssp_f(acc[i][0]); o.y = ssp_f(acc[i][1]);
            o.z = ssp_f(acc[i][2]); o.w = ssp_f(acc[i][3]);
            *(float4*)&t_s[eb + i][c4] = o;
        }
    }
    __syncthreads();
    {
        const float4 bv = *(const float4*)(b2 + c4);
        #pragma unroll
        for (int i = 0; i < 4; ++i) { acc[i][0]=bv.x; acc[i][1]=bv.y; acc[i][2]=bv.z; acc[i][3]=bv.w; }
        #pragma unroll 4
        for (int k = 0; k < 128; ++k) {
            const float4 wv = *(const float4*)(w2 + k * 128 + c4);
            #pragma unroll
            for (int i = 0; i < 4; ++i) {
                const float a = t_s[eb + i][k];
                acc[i][0] += a * wv.x; acc[i][1] += a * wv.y;
                acc[i][2] += a * wv.z; acc[i][3] += a * wv.w;
            }
        }
    }
    #pragma unroll
    for (int i = 0; i < 4; ++i) {
        const int e = eb + i;
        if (e0 + e >= E) continue;
        const float Ce = C_s[e];
        const float4 xv = *(const float4*)(xh + (long)row_s[e] * 128 + c4);
        float* ag = agg + (long)col_s[e] * 128 + c4;
        atomicAdd(ag + 0, acc[i][0] * Ce * xv.x);
        atomicAdd(ag + 1, acc[i][1] * Ce * xv.y);
        atomicAdd(ag + 2, acc[i][2] * Ce * xv.z);
        atomicAdd(ag + 3, acc[i][3] * Ce * xv.w);
    }
}

// ---------------- MFMA readout, 16-row tile ------------------------------------
__global__ __launch_bounds__(256) void readout_mfma(
    const float* __restrict__ h, const unsigned short* __restrict__ o1t,
    const float* __restrict__ o1b, const float* __restrict__ o2w,
    const float* __restrict__ o2b, const int* __restrict__ batch,
    float* __restrict__ accb, int N)
{
    __shared__ __align__(16) short a_b[16][136];
    __shared__ float nb[16];
    const int t = threadIdx.x;
    const long r0 = (long)blockIdx.x * 16;
    #pragma unroll
    for (int j = 0; j < 2; ++j) {
        const int fi = t + j * 256;
        const int r = fi >> 5, c4 = (fi & 31) << 2;
        const long n = r0 + r;
        float4 v = make_float4(0.f, 0.f, 0.f, 0.f);
        if (n < N) v = *(const float4*)(h + n * 128 + c4);
        *(uint2*)&a_b[r][c4] = make_uint2(pk2(v.x, v.y), pk2(v.z, v.w));
    }
    if (t < 16) nb[t] = 0.f;
    __syncthreads();
    const int lane = t & 63, w = t >> 6;
    const int colL = lane & 15, quad = lane >> 4;
    const int nh = w * 16;                  // 4 waves x 16 = 64 out1 channels
    f32x4 acc = (f32x4){0.f, 0.f, 0.f, 0.f};
    #pragma unroll
    for (int ks = 0; ks < 4; ++ks) {
        const bfrag a = *(const bfrag*)&a_b[colL][ks * 32 + quad * 8];
        const bfrag wf = *(const bfrag*)&o1t[(long)(nh + colL) * 128 + ks * 32 + quad * 8];
        acc = __builtin_amdgcn_mfma_f32_16x16x32_bf16(wf, a, acc, 0, 0, 0);
    }
    float s = 0.f;
    {
        const int c0 = nh + quad * 4;
        const float4 bv = *(const float4*)(o1b + c0);
        const float4 wv = *(const float4*)(o2w + c0);
        s += ssp_f(acc[0] + bv.x) * wv.x;
        s += ssp_f(acc[1] + bv.y) * wv.y;
        s += ssp_f(acc[2] + bv.z) * wv.z;
        s += ssp_f(acc[3] + bv.w) * wv.w;
    }
    s += __shfl_xor(s, 16);
    s += __shfl_xor(s, 32);
    if (quad == 0) atomicAdd(&nb[colL], s);
    __syncthreads();
    if (t < 16) {
        const long node = r0 + t;
        if (node < N) atomicAdd(&accb[batch[node]], nb[t] + o2b[0]);
    }
}

// ---------------- simple readout (fallback path) -------------------------------
__global__ __launch_bounds__(128) void readout_simple(
    const float* __restrict__ h,
    const float* __restrict__ o1w, const float* __restrict__ o1b,
    const float* __restrict__ o2w, const float* __restrict__ o2b,
    const int* __restrict__ batch, float* __restrict__ accb)
{
    __shared__ float hr[128];
    __shared__ float vv[64];
    const int n = blockIdx.x;
    const int t = threadIdx.x;
    hr[t] = h[(long)n * 128 + t];
    __syncthreads();
    if (t < 64) {
        float a = o1b[t];
        #pragma unroll 8
        for (int k = 0; k < 128; ++k)
            a = fmaf(hr[k], o1w[k * 64 + t], a);
        vv[t] = ssp_f(a) * o2w[t];
    }
    __syncthreads();
    if (t < 32) vv[t] += vv[t + 32];
    __syncthreads();
    if (t < 16) vv[t] += vv[t + 16];
    __syncthreads();
    if (t < 8)  vv[t] += vv[t + 8];
    __syncthreads();
    if (t < 4)  vv[t] += vv[t + 4];
    __syncthreads();
    if (t < 2)  vv[t] += vv[t + 2];
    __syncthreads();
    if (t == 0) atomicAdd(&accb[batch[n]], vv[0] + vv[1] + o2b[0]);
}

// output is FLOAT32 (verified round 11)
__global__ void finalize_kernel(const float* __restrict__ accb,
                                float* __restrict__ out, int B)
{
    int t = blockIdx.x * 256 + threadIdx.x;
    if (t < B) out[t] = accb[t];
}

// ---------------- launch -------------------------------------------------------
extern "C" void kernel_launch(void* const* d_in, const int* in_sizes, int n_in,
                              void* d_out, int out_size, void* d_ws, size_t ws_size,
                              hipStream_t stream)
{
    const int N   = in_sizes[0];
    const int E   = in_sizes[3] / 2;
    const int B   = out_size;
    const int H   = 128;
    const int L   = in_sizes[7] / H;
    const int NB  = in_sizes[4] / E;
    const int F50 = in_sizes[6] / (L * H);
    const int NGS = F50 - NB;
    const float delta = 10.0f / (float)(NGS - 1);
    const float coeff = -0.5f / (delta * delta);

    const int fidx[16] = {1, 4, 5, 6, 7, 8, 9, 10, 11, 12, 13, 14, 15, 16, 17, 18};
    Cvt16 cv;
    cv.off[0] = 0;
    for (int i = 0; i < 16; ++i) {
        cv.src[i] = d_in[fidx[i]];
        cv.off[i + 1] = cv.off[i] + in_sizes[fidx[i]];
    }
    const long ftot = cv.off[16];

    float* F = (float*)d_ws;
    long base = (ftot + 3) & ~3L;
    float* h    = F + base;
    float* xh   = h + (long)N * H;
    float* agg  = xh + (long)N * H;
    float* accb = agg + (long)N * H;
    int*   flag  = (int*)(accb + ((B + 3) & ~3));
    int*   iflag = flag + 1;
    int*   zi     = flag + 4;
    int*   batchi = zi + N;
    int*   eidxi  = batchi + N;
    int*   count  = eidxi + 2 * E;
    int*   rowptr = count + N;
    int*   next   = rowptr + N + 1;
    int*   rowS   = next + N;
    int*   colS   = rowS + E;
    float* CS     = (float*)(colS + E);
    float* ewS    = CS + E;
    unsigned short* eaS = (unsigned short*)(ewS + E);      // 4E ushorts
    unsigned short* w1t = eaS + 4L * E;                    // L*128*64
    unsigned short* w2t = w1t + (long)L * 128 * 64;        // L*128*128
    unsigned short* nwt = w2t + (long)L * 128 * 128;       // 3L*128*128
    unsigned short* o1t = nwt + 3L * L * 128 * 128;        // 64*128
    long used_bytes = (long)((char*)(o1t + 64 * 128) - (char*)d_ws);
    const bool use_fast = (used_bytes <= (long)ws_size) && (F50 <= 64) && (NB <= 4);

    sniff_kernel<<<1, 256, 0, stream>>>((const unsigned int*)d_in[5], flag);
    sniff_int_kernel<<<1, 128, 0, stream>>>((const unsigned int*)d_in[0], iflag);

    convert_fused_kernel<<<(int)((ftot + 255) / 256), 256, 0, stream>>>(cv, F, ftot, flag);
    convert_int_kernel<<<(N + 255) / 256, 256, 0, stream>>>(d_in[0], zi, N, iflag);
    convert_int_kernel<<<(N + 255) / 256, 256, 0, stream>>>(d_in[2], batchi, N, iflag);
    convert_int_kernel<<<(2 * E + 255) / 256, 256, 0, stream>>>(d_in[3], eidxi, 2 * E, iflag);

    const float* posf   = F + cv.off[0];
    const float* eattrf = F + cv.off[1];
    const float* embf   = F + cv.off[2];
    const float* w1   = F + cv.off[3];  const float* b1   = F + cv.off[4];
    const float* w2   = F + cv.off[5];  const float* b2   = F + cv.off[6];
    const float* cf1  = F + cv.off[7];  const float* cf2  = F + cv.off[8];
    const float* cf2b = F + cv.off[9];  const float* lin  = F + cv.off[10];
    const float* linb = F + cv.off[11]; const float* o1   = F + cv.off[12];
    const float* o1b  = F + cv.off[13]; const float* o2   = F + cv.off[14];
    const float* o2b  = F + cv.off[15];

    if (use_fast) {
        zero_int_kernel<<<(N + 255) / 256, 256, 0, stream>>>(count, N);
        hist_kernel<<<(E + 255) / 256, 256, 0, stream>>>(eidxi + E, count, E);
        scan_kernel<<<1, 256, 0, stream>>>(count, rowptr, next, N);
        prep_scatter_kernel<<<(E + 255) / 256, 256, 0, stream>>>(
            posf, eidxi, eidxi + E, eattrf, next, rowS, colS, CS, ewS, eaS, E, NB);
        const int wt_total = L * 8192 + L * 16384 + 3 * L * 16384 + 8192;
        wtrans_all_kernel<<<(wt_total + 255) / 256, 256, 0, stream>>>(
            w1, w2, cf1, cf2, lin, o1, w1t, w2t, nwt, o1t, L, F50, wt_total);
    }

    hipMemsetAsync(accb, 0, (size_t)B * sizeof(float), stream);

    const int ngemm16 = (N + 15) / 16;
    const int nedge   = (E + 31) / 32;
    if (use_fast) {
        node_gemm1_embed_mfma<<<ngemm16, 256, 0, stream>>>(
            zi, embf, nwt + 0, h, xh, agg, N);
        for (int l = 0; l < L; ++l) {
            edge_mfma<<<nedge, 256, 0, stream>>>(
                rowS, colS, CS, ewS, eaS,
                w1t + (long)l * 128 * 64, b1 + (long)l * H,
                w2t + (long)l * 128 * 128, b2 + (long)l * H,
                xh, agg, E, NB, F50, delta, coeff);
            if (l < L - 1) {
                node_gemm23_mfma<1><<<ngemm16, 256, 0, stream>>>(
                    agg, nwt + (long)(l * 3 + 1) * 16384, cf2b + (long)l * H,
                    nwt + (long)(l * 3 + 2) * 16384, linb + (long)l * H, h,
                    nwt + (long)((l + 1) * 3 + 0) * 16384, xh, agg, N);
            } else {
                node_gemm23_mfma<0><<<ngemm16, 256, 0, stream>>>(
                    agg, nwt + (long)(l * 3 + 1) * 16384, cf2b + (long)l * H,
                    nwt + (long)(l * 3 + 2) * 16384, linb + (long)l * H, h,
                    nullptr, nullptr, nullptr, N);
            }
        }
        readout_mfma<<<ngemm16, 256, 0, stream>>>(h, o1t, o1b, o2, o2b, batchi, accb, N);
    } else {
        embed_kernel<<<(N * H + 255) / 256, 256, 0, stream>>>(zi, embf, h, N * H);
        const int ngemm32 = (N + 31) / 32;
        for (int l = 0; l < L; ++l) {
            hipMemsetAsync(agg, 0, (size_t)N * H * sizeof(float), stream);
            node_gemm_tiled<0><<<ngemm32, 256, 0, stream>>>(h, cf1 + (long)l * H * H, nullptr, xh, N);
            edge_atomic<<<nedge, 256, 0, stream>>>(
                posf, eidxi, eidxi + E, eattrf,
                w1 + (long)l * F50 * H, b1 + (long)l * H,
                w2 + (long)l * H * H,  b2 + (long)l * H,
                xh, agg, E, NB, F50, delta, coeff);
            node_gemm_tiled<1><<<ngemm32, 256, 0, stream>>>(agg, cf2 + (long)l * H * H, cf2b + (long)l * H, xh, N);
            node_gemm_tiled<2><<<ngemm32, 256, 0, stream>>>(xh, lin + (long)l * H * H, linb + (long)l * H, h, N);
        }
        readout_simple<<<N, 128, 0, stream>>>(h, o1, o1b, o2, o2b, batchi, accb);
    }
    finalize_kernel<<<(B + 255) / 256, 256, 0, stream>>>(accb, (float*)d_out, B);
}